// Round 16
// baseline (241.730 us; speedup 1.0000x reference)
//
#include <hip/hip_runtime.h>
#include <stdint.h>

#define NB 16
#define NH 8
#define LQ 1024
#define LKV 1424
#define LKVP 1472
#define DIMC 384
#define NKVT 23
#define TEM 400
#define QSCALE 0.20823509f       // (1/sqrt(48)) * log2(e)
#define LOG2E_F 1.4426950408889634f
#define POSF_OFF 114360320ull
#define POSF_END 162594816ull

typedef __attribute__((ext_vector_type(4))) float f32x4;
typedef __attribute__((ext_vector_type(8))) short bf16x8;
typedef __attribute__((ext_vector_type(4))) unsigned short us4;
typedef __attribute__((ext_vector_type(2))) unsigned int u32x2;
typedef __attribute__((ext_vector_type(4))) unsigned int u32x4;

__device__ __forceinline__ unsigned short f2b(float f) {
  unsigned int u = __builtin_bit_cast(unsigned int, f);
  u += 0x7fffu + ((u >> 16) & 1u);  // round-to-nearest-even
  return (unsigned short)(u >> 16);
}

__device__ __forceinline__ void gload_lds16(const void* gsrc, void* ldst) {
  __builtin_amdgcn_global_load_lds(
      (const __attribute__((address_space(1))) void*)gsrc,
      (__attribute__((address_space(3))) void*)ldst, 16, 0, 0);
}

// ---------- merged prep: convert(5) + pad-zero + pos-pack (one launch) ----------
__global__ __launch_bounds__(256) void prep_all(
    const float* __restrict__ q, const float* __restrict__ kv,
    const float* __restrict__ qw, const float* __restrict__ kvw,
    const float* __restrict__ pw, const float* __restrict__ pos,
    unsigned short* __restrict__ qb, unsigned short* __restrict__ kvb,
    unsigned short* __restrict__ qwb, unsigned short* __restrict__ kvwb,
    unsigned short* __restrict__ pwb, unsigned short* __restrict__ Qp,
    unsigned short* __restrict__ Kp, unsigned short* __restrict__ Vt,
    unsigned short* __restrict__ posb, float* __restrict__ posf, int f32pos) {
  __shared__ float lds[4][1024];
  const int bid = blockIdx.x;
  if (bid < 7632) {  // ---- conv: f32 [R][384] -> bf16 pre-swizzled ----
    int i = bid * 256 + threadIdx.x;
    const float* src;
    unsigned short* dst;
    if (i < 16384 * 48) { src = q; dst = qb; }
    else if (i < 39168 * 48) { i -= 16384 * 48; src = kv; dst = kvb; }
    else if (i < 39552 * 48) { i -= 39168 * 48; src = qw; dst = qwb; }
    else if (i < 40320 * 48) { i -= 39552 * 48; src = kvw; dst = kvwb; }
    else { i -= 40320 * 48; src = pw; dst = pwb; }
    int row = i / 48, ch = i - row * 48;
    const float* sp = src + (size_t)row * DIMC + ch * 8;
    f32x4 x = *(const f32x4*)sp;
    f32x4 y = *(const f32x4*)(sp + 4);
    bf16x8 o;
    o[0] = (short)f2b(x[0]); o[1] = (short)f2b(x[1]);
    o[2] = (short)f2b(x[2]); o[3] = (short)f2b(x[3]);
    o[4] = (short)f2b(y[0]); o[5] = (short)f2b(y[1]);
    o[6] = (short)f2b(y[2]); o[7] = (short)f2b(y[3]);
    int blk = ch >> 3, c3 = (ch & 7) ^ (row & 7);
    *(bf16x8*)(dst + (size_t)row * DIMC + blk * 64 + c3 * 8) = o;
  } else if (bid < 9024) {  // ---- exact pad zeroing ----
    int i = (bid - 7632) * 256 + threadIdx.x;
    u32x4 z = {0u, 0u, 0u, 0u};
    if (i < 131072) {
      *(u32x4*)(Qp + (size_t)i * 64 + 48) = z;
      *(u32x4*)(Qp + (size_t)i * 64 + 56) = z;
    } else if (i < 131072 + 188416) {
      int r = i - 131072;
      int s = r % LKVP;
      unsigned short* row = Kp + (size_t)r * 64;
      if (s < LKV) {
        *(u32x4*)(row + (6 ^ (s & 7)) * 8) = z;
        *(u32x4*)(row + (7 ^ (s & 7)) * 8) = z;
      } else {
#pragma unroll
        for (int c = 0; c < 64; c += 8) *(u32x4*)(row + c) = z;
      }
    } else if (i < 131072 + 188416 + 36864) {
      int j = i - 319488;
      int row = j / 6, x = 2 + j - (j / 6) * 6;
      int d = row % 48;
      *(u32x4*)(Vt + (size_t)row * LKVP + 1408 + ((x ^ d) & 7) * 8) = z;
    }
  } else {  // ---- pos pack: coalesced reads, LDS transpose, fragment order ----
    const int r = bid - 9024;
    const int q16 = r & 63, h = r >> 6;
    const int wave = threadIdx.x >> 6, lane = threadIdx.x & 63;
    const int l16 = lane & 15, g = lane >> 4;
    float* L = &lds[wave][0];
    for (int t = wave; t < NKVT; t += 4) {
#pragma unroll
      for (int i = 0; i < 4; ++i) {
        const int row = i * 4 + g;
        const int gcol = t * 64 + l16 * 4;
        f32x4 v;
        if (gcol < LKV) {
          v = *(const f32x4*)(pos + ((size_t)h * LQ + q16 * 16 + row) * LKV + gcol);
          v *= LOG2E_F;
        } else {
          f32x4 neg = {-1e30f, -1e30f, -1e30f, -1e30f};
          v = neg;
        }
        *(f32x4*)(L + row * 64 + ((l16 ^ (row & 7)) << 2)) = v;
      }
      if (f32pos) {
        float* op = posf + ((((size_t)h * 64 + q16) * NKVT + t) * 64 + lane) * 16;
#pragma unroll
        for (int ni = 0; ni < 4; ++ni) {
          f32x4 wv = *(const f32x4*)(L + l16 * 64 + (((4 * ni + g) ^ (l16 & 7)) << 2));
          *(f32x4*)(op + 4 * ni) = wv;
        }
      } else {
        unsigned short vals[16];
#pragma unroll
        for (int ni = 0; ni < 4; ++ni) {
          f32x4 wv = *(const f32x4*)(L + l16 * 64 + (((4 * ni + g) ^ (l16 & 7)) << 2));
#pragma unroll
          for (int rr = 0; rr < 4; ++rr) vals[4 * ni + rr] = f2b(wv[rr]);
        }
        unsigned short* op = posb + ((((size_t)h * 64 + q16) * NKVT + t) * 64 + lane) * 16;
        bf16x8 a, b;
#pragma unroll
        for (int k = 0; k < 8; ++k) { a[k] = (short)vals[k]; b[k] = (short)vals[8 + k]; }
        *(bf16x8*)op = a;
        *(bf16x8*)(op + 8) = b;
      }
    }
  }
}

// ---------- projection GEMM body: 128x128 tile, BK=64, gload_lds staging ----------
template <int MODE>
__device__ __forceinline__ void proj_body(
    unsigned short* Ash, unsigned short* Bsh, int n0, int m0,
    const unsigned short* __restrict__ A, const unsigned short* __restrict__ Wb,
    const float* __restrict__ bias, const float* __restrict__ tem,
    const float* __restrict__ srch, unsigned short* __restrict__ Oq,
    unsigned short* __restrict__ Ok, unsigned short* __restrict__ Ovt,
    float* __restrict__ Of) {
  const int tid = threadIdx.x;
  const int lane = tid & 63, l16 = lane & 15, g = lane >> 4;
  const int wave = tid >> 6, wm = wave >> 1, wn = wave & 1;

  f32x4 acc[4][4];
#pragma unroll
  for (int i = 0; i < 4; ++i)
#pragma unroll
    for (int j = 0; j < 4; ++j) { f32x4 z = {0.f, 0.f, 0.f, 0.f}; acc[i][j] = z; }

  const char* Abase = (const char*)A + (size_t)m0 * 768;
  const char* Bbase = (const char*)Wb + (size_t)n0 * 768;

  for (int ks = 0; ks < 6; ++ks) {
    __syncthreads();
#pragma unroll
    for (int rnd = 0; rnd < 4; ++rnd) {
      int idx = tid + rnd * 256;
      int row = idx >> 3, chunk = idx & 7;
      gload_lds16(Abase + (size_t)row * 768 + ks * 128 + chunk * 16,
                  (char*)Ash + idx * 16);
    }
#pragma unroll
    for (int rnd = 0; rnd < 4; ++rnd) {
      int idx = tid + rnd * 256;
      int row = idx >> 3, chunk = idx & 7;
      gload_lds16(Bbase + (size_t)row * 768 + ks * 128 + chunk * 16,
                  (char*)Bsh + idx * 16);
    }
    asm volatile("s_waitcnt vmcnt(0)" ::: "memory");
    __syncthreads();
#pragma unroll
    for (int kk = 0; kk < 2; ++kk) {
      bf16x8 a[4], bb[4];
#pragma unroll
      for (int mi = 0; mi < 4; ++mi) {
        int row = wm * 64 + mi * 16 + l16;
        a[mi] = *(const bf16x8*)((char*)Ash + row * 128 + (((g + 4 * kk) ^ (row & 7)) << 4));
      }
#pragma unroll
      for (int ni = 0; ni < 4; ++ni) {
        int row = wn * 64 + ni * 16 + l16;
        bb[ni] = *(const bf16x8*)((char*)Bsh + row * 128 + (((g + 4 * kk) ^ (row & 7)) << 4));
      }
#pragma unroll
      for (int mi = 0; mi < 4; ++mi)
#pragma unroll
        for (int ni = 0; ni < 4; ++ni)
          acc[mi][ni] = __builtin_amdgcn_mfma_f32_16x16x32_bf16(a[mi], bb[ni], acc[mi][ni], 0, 0, 0);
    }
  }

#pragma unroll
  for (int mi = 0; mi < 4; ++mi) {
    const int m_g0 = m0 + wm * 64 + mi * 16 + 4 * g;
#pragma unroll
    for (int ni = 0; ni < 4; ++ni) {
      const int n_g = n0 + wn * 64 + ni * 16 + l16;
      const float bv = bias[n_g];
      if (MODE == 0) {
        const int hh = n_g / 48, d = n_g - hh * 48;
#pragma unroll
        for (int r = 0; r < 4; ++r) {
          const int m_g = m_g0 + r;
          const int b = m_g >> 10, m = m_g & 1023;
          Oq[(((size_t)b * NH + hh) * LQ + m) * 64 + d] = f2b((acc[mi][ni][r] + bv) * QSCALE);
        }
      } else if (MODE == 2) {
#pragma unroll
        for (int r = 0; r < 4; ++r)
          Of[(size_t)(m_g0 + r) * DIMC + n_g] = acc[mi][ni][r] + bv;
      } else {
        const int b = m_g0 / LKV, s0 = m_g0 - b * LKV;
        if (n_g < DIMC) {
          const int hh = n_g / 48, d = n_g - hh * 48;
#pragma unroll
          for (int r = 0; r < 4; ++r) {
            const int s = s0 + r;
            const int dsw = (d & 7) | ((((d >> 3) ^ (s & 7)) & 7) << 3);
            Ok[(((size_t)b * NH + hh) * LKVP + s) * 64 + dsw] = f2b(acc[mi][ni][r] + bv);
          }
        } else {
          const int c = n_g - DIMC, hh = c / 48, d = c - hh * 48;
          const float* mb = (s0 < TEM)
                                ? tem + ((size_t)b * TEM + s0) * DIMC + c
                                : srch + ((size_t)b * (LKV - TEM) + (s0 - TEM)) * DIMC + c;
          const int off = s0 & 63;
          const int soff = (s0 & ~63) | ((((off >> 3) ^ d) & 7) << 3) | (off & 7);
          us4 pk;
#pragma unroll
          for (int r = 0; r < 4; ++r)
            pk[r] = f2b(acc[mi][ni][r] + bv + mb[(size_t)r * DIMC]);
          *(us4*)(Ovt + (((size_t)b * NH + hh) * 48 + d) * LKVP + soff) = pk;
        }
      }
    }
  }
}

// fused Q-proj (384 blocks) + KV-proj (1068 blocks)
__global__ __launch_bounds__(256) void proj_qkv(
    const unsigned short* __restrict__ qb, const unsigned short* __restrict__ qwb,
    const float* __restrict__ q_b, const unsigned short* __restrict__ kvb,
    const unsigned short* __restrict__ kvwb, const float* __restrict__ kv_b,
    const float* __restrict__ tem, const float* __restrict__ srch,
    unsigned short* __restrict__ Qp, unsigned short* __restrict__ Ok,
    unsigned short* __restrict__ Ovt) {
  __shared__ unsigned short Ash[128 * 64];
  __shared__ unsigned short Bsh[128 * 64];
  const int bid = blockIdx.x;
  if (bid < 384) {
    proj_body<0>(Ash, Bsh, (bid % 3) * 128, (bid / 3) * 128, qb, qwb, q_b,
                 nullptr, nullptr, Qp, nullptr, nullptr, nullptr);
  } else {
    const int r = bid - 384;
    proj_body<1>(Ash, Bsh, (r % 6) * 128, (r / 6) * 128, kvb, kvwb, kv_b,
                 tem, srch, nullptr, Ok, Ovt, nullptr);
  }
}

__global__ __launch_bounds__(256) void proj_out(
    const unsigned short* __restrict__ X, const unsigned short* __restrict__ pwb,
    const float* __restrict__ p_b, float* __restrict__ out) {
  __shared__ unsigned short Ash[128 * 64];
  __shared__ unsigned short Bsh[128 * 64];
  proj_body<2>(Ash, Bsh, (blockIdx.x % 3) * 128, (blockIdx.x / 3) * 128, X, pwb, p_b,
               nullptr, nullptr, nullptr, nullptr, nullptr, out);
}

// ---------------- flash attention ----------------
// R15-verified dataflow. F32POS=1: pos stored f32 fragment-ordered, loaded DIRECTLY
// into the QK accumulators (zero unpack VALU), reloaded for t+1 right after packP
// kills the register. F32POS=0: byte-identical R15 bf16 path (ws-size fallback).
__device__ __forceinline__ void stage_tile(const char* kbase, const char* vbase, int t,
                                           char* kdst, char* vdst, int wave, int lane) {
  const char* ks = kbase + (size_t)t * 8192 + wave * 2048 + lane * 16;
  char* kd = kdst + wave * 2048;
  gload_lds16(ks, kd);
  gload_lds16(ks + 1024, kd + 1024);
  if (wave < 3) {  // V tile: 48 rows x 128B
    const char* vs = vbase + (size_t)(wave * 16 + (lane >> 3)) * (LKVP * 2) +
                     (size_t)t * 128 + (lane & 7) * 16;
    char* vd = vdst + wave * 2048;
    gload_lds16(vs, vd);
    gload_lds16(vs + 8 * (LKVP * 2), vd + 1024);
  }
}

__device__ __forceinline__ void exp16(f32x4 (&sx)[4]) {
#pragma unroll
  for (int ni = 0; ni < 4; ++ni)
#pragma unroll
    for (int r = 0; r < 4; ++r) sx[ni][r] = exp2f(sx[ni][r]);
}

__device__ __forceinline__ void packP(const f32x4 (&sx)[4], char* pbase, int swz, int g,
                                      bf16x8& af0, bf16x8& af1) {
#pragma unroll
  for (int ni = 0; ni < 4; ++ni) {
    float e0 = sx[ni][0], e1 = sx[ni][1], e2 = sx[ni][2], e3 = sx[ni][3];
    unsigned int lo, hi;
    asm("v_cvt_pk_bf16_f32 %0, %1, %2" : "=v"(lo) : "v"(e0), "v"(e1));
    asm("v_cvt_pk_bf16_f32 %0, %1, %2" : "=v"(hi) : "v"(e2), "v"(e3));
    u32x2 pk = {lo, hi};
    *(u32x2*)(pbase + ((32 * ni + 8 * g) ^ swz)) = pk;
  }
  af0 = *(const bf16x8*)(pbase + ((16 * g) ^ swz));
  af1 = *(const bf16x8*)(pbase + ((64 + 16 * g) ^ swz));
}

__device__ __forceinline__ void unpack_pos(const u32x4& w0, const u32x4& w1,
                                           f32x4 (&s)[4]) {
#pragma unroll
  for (int k = 0; k < 4; ++k) {
    const int ni = k >> 1, j2 = (k & 1) * 2;
    unsigned int a = w0[k], b = w1[k];
    s[ni][j2]         = __builtin_bit_cast(float, a << 16);
    s[ni][j2 + 1]     = __builtin_bit_cast(float, a & 0xffff0000u);
    s[ni + 2][j2]     = __builtin_bit_cast(float, b << 16);
    s[ni + 2][j2 + 1] = __builtin_bit_cast(float, b & 0xffff0000u);
  }
}

template <int F32POS>
__global__ __launch_bounds__(256, 4) void attn_fwd(
    const unsigned short* __restrict__ posb, const float* __restrict__ posf,
    const unsigned short* __restrict__ Qp, const unsigned short* __restrict__ Kp,
    const unsigned short* __restrict__ Vt, unsigned short* __restrict__ X) {
  __shared__ unsigned short Ksh[2][64 * 64];
  __shared__ unsigned short Vsh[2][48 * 64];
  __shared__ unsigned short Psh[4][16 * 64];

  const int tid = threadIdx.x;
  const int lane = tid & 63, l16 = lane & 15, g = lane >> 4;
  const int wave = tid >> 6;
  const int bid = blockIdx.x;  // xcd = bid%8 = h (L2 locality)
  const int bh = bid & 127, qt = bid >> 7;
  const int b = bh >> 3, h = bh & 7;
  const int qrow = qt * 128 + wave * 32;

  bf16x8 qf[2][2];
#pragma unroll
  for (int qs = 0; qs < 2; ++qs) {
    const unsigned short* qb = Qp + ((size_t)bh * LQ + qrow + qs * 16 + l16) * 64 + 8 * g;
    qf[qs][0] = *(const bf16x8*)qb;
    qf[qs][1] = *(const bf16x8*)(qb + 32);
  }

  bf16x8 ones;
#pragma unroll
  for (int i = 0; i < 8; ++i) ones[i] = (short)0x3F80;  // bf16 1.0

  f32x4 lsum[2];
  f32x4 o[2][3];
#pragma unroll
  for (int qs = 0; qs < 2; ++qs) {
    f32x4 z = {0.f, 0.f, 0.f, 0.f};
    lsum[qs] = z;
#pragma unroll
    for (int d = 0; d < 3; ++d) o[qs][d] = z;
  }

  const char* kbase = (const char*)(Kp + (size_t)bh * LKVP * 64);
  const char* vbase = (const char*)(Vt + (size_t)bh * 48 * LKVP);
  const int q16b = qt * 8 + wave * 2;
  const unsigned short* pq0 = posb + (((size_t)h * 64 + q16b) * NKVT) * 1024 + lane * 16;
  const unsigned short* pq1 = pq0 + (size_t)NKVT * 1024;
  const float* pf0 = posf + (((size_t)h * 64 + q16b) * NKVT) * 1024 + lane * 16;
  const float* pf1 = pf0 + (size_t)NKVT * 1024;
  char* pbase = (char*)&Psh[wave][0] + l16 * 128;
  const int swz = (l16 & 7) << 4;

  stage_tile(kbase, vbase, 0, (char*)&Ksh[0][0], (char*)&Vsh[0][0], wave, lane);

  f32x4 s0[4], s1[4];
  u32x4 w0, w1, w2, w3;
  if constexpr (F32POS) {
#pragma unroll
    for (int ni = 0; ni < 4; ++ni) {
      s0[ni] = *(const f32x4*)(pf0 + 4 * ni);
      s1[ni] = *(const f32x4*)(pf1 + 4 * ni);
    }
    pf0 += 1024; pf1 += 1024;
  } else {
    w0 = *(const u32x4*)(pq0);
    w1 = *(const u32x4*)(pq0 + 8);
    w2 = *(const u32x4*)(pq1);
    w3 = *(const u32x4*)(pq1 + 8);
    pq0 += 1024; pq1 += 1024;
  }

  asm volatile("s_waitcnt vmcnt(0)" ::: "memory");
  __syncthreads();

  int buf = 0;
  for (int t = 0; t < NKVT; ++t) {
    if (t + 1 < NKVT)
      stage_tile(kbase, vbase, t + 1, (char*)&Ksh[buf ^ 1][0], (char*)&Vsh[buf ^ 1][0],
                 wave, lane);

    if constexpr (!F32POS) {
      unpack_pos(w0, w1, s0);
      unpack_pos(w2, w3, s1);
      if (t + 1 < NKVT) {
        w0 = *(const u32x4*)(pq0);
        w1 = *(const u32x4*)(pq0 + 8);
        w2 = *(const u32x4*)(pq1);
        w3 = *(const u32x4*)(pq1 + 8);
        pq0 += 1024; pq1 += 1024;
      }
    }

    // QK^T swapped (q = l16 lane-local), C initialized with pos
#pragma unroll
    for (int ni = 0; ni < 4; ++ni) {
      const int krow = ni * 16 + l16;
      const char* kr = (const char*)&Ksh[buf][0] + krow * 128;
      bf16x8 kf0 = *(const bf16x8*)(kr + ((g ^ (krow & 7)) << 4));
      bf16x8 kf1 = *(const bf16x8*)(kr + (((g + 4) ^ (krow & 7)) << 4));
      s0[ni] = __builtin_amdgcn_mfma_f32_16x16x32_bf16(kf0, qf[0][0], s0[ni], 0, 0, 0);
      s0[ni] = __builtin_amdgcn_mfma_f32_16x16x32_bf16(kf1, qf[0][1], s0[ni], 0, 0, 0);
      s1[ni] = __builtin_amdgcn_mfma_f32_16x16x32_bf16(kf0, qf[1][0], s1[ni], 0, 0, 0);
      s1[ni] = __builtin_amdgcn_mfma_f32_16x16x32_bf16(kf1, qf[1][1], s1[ni], 0, 0, 0);
    }

    // P = exp2(s) (bounded logits); l via ones-MFMA on matrix pipe.
    exp16(s0);
    bf16x8 af00, af01, af10, af11;
    packP(s0, pbase, swz, g, af00, af01);
    if constexpr (F32POS) {
      if (t + 1 < NKVT) {  // s0 dead after pack — reload pos(t+1) directly
#pragma unroll
        for (int ni = 0; ni < 4; ++ni) s0[ni] = *(const f32x4*)(pf0 + 4 * ni);
        pf0 += 1024;
      }
    }
    exp16(s1);
#pragma unroll
    for (int dn = 0; dn < 3; ++dn) {
      const int vr = 16 * dn + l16;
      const char* vrp = (const char*)&Vsh[buf][0] + vr * 128;
      bf16x8 vf0 = *(const bf16x8*)(vrp + ((g ^ (vr & 7)) << 4));
      bf16x8 vf1 = *(const bf16x8*)(vrp + (((g + 4) ^ (vr & 7)) << 4));
      o[0][dn] = __builtin_amdgcn_mfma_f32_16x16x32_bf16(af00, vf0, o[0][dn], 0, 0, 0);
      o[0][dn] = __builtin_amdgcn_mfma_f32_16x16x32_bf16(af01, vf1, o[0][dn], 0, 0, 0);
    }
    lsum[0] = __builtin_amdgcn_mfma_f32_16x16x32_bf16(af00, ones, lsum[0], 0, 0, 0);
    lsum[0] = __builtin_amdgcn_mfma_f32_16x16x32_bf16(af01, ones, lsum[0], 0, 0, 0);
    packP(s1, pbase, swz, g, af10, af11);
    if constexpr (F32POS) {
      if (t + 1 < NKVT) {
#pragma unroll
        for (int ni = 0; ni < 4; ++ni) s1[ni] = *(const f32x4*)(pf1 + 4 * ni);
        pf1 += 1024;
      }
    }
#pragma unroll
    for (int dn = 0; dn < 3; ++dn) {
      const int vr = 16 * dn + l16;
      const char* vrp = (const char*)&Vsh[buf][0] + vr * 128;
      bf16x8 vf0 = *(const bf16x8*)(vrp + ((g ^ (vr & 7)) << 4));
      bf16x8 vf1 = *(const bf16x8*)(vrp + (((g + 4) ^ (vr & 7)) << 4));
      o[1][dn] = __builtin_amdgcn_mfma_f32_16x16x32_bf16(af10, vf0, o[1][dn], 0, 0, 0);
      o[1][dn] = __builtin_amdgcn_mfma_f32_16x16x32_bf16(af11, vf1, o[1][dn], 0, 0, 0);
    }
    lsum[1] = __builtin_amdgcn_mfma_f32_16x16x32_bf16(af10, ones, lsum[1], 0, 0, 0);
    lsum[1] = __builtin_amdgcn_mfma_f32_16x16x32_bf16(af11, ones, lsum[1], 0, 0, 0);

    asm volatile("s_waitcnt vmcnt(0)" ::: "memory");
    __syncthreads();
    buf ^= 1;
  }

  // epilogue: lsum[qs][r] indexed by q = 4g+r (same C-layout as o) — no shfl
#pragma unroll
  for (int qs = 0; qs < 2; ++qs) {
#pragma unroll
    for (int r = 0; r < 4; ++r) {
      const float ib = 1.f / lsum[qs][r];
      const int m = qrow + qs * 16 + 4 * g + r;
#pragma unroll
      for (int dn = 0; dn < 3; ++dn) {
        const int c = h * 48 + 16 * dn + l16;
        const int cs = (c & ~63) | (c & 7) | ((((c >> 3) & 7) ^ (m & 7)) << 3);
        X[((size_t)b * LQ + m) * DIMC + cs] = f2b(o[qs][dn][r] * ib);
      }
    }
  }
}

// ---------------- launch ----------------
extern "C" void kernel_launch(void* const* d_in, const int* in_sizes, int n_in,
                              void* d_out, int out_size, void* d_ws, size_t ws_size,
                              hipStream_t stream) {
  const float* tem  = (const float*)d_in[0];
  const float* srch = (const float*)d_in[1];
  const float* q    = (const float*)d_in[2];
  const float* kv   = (const float*)d_in[3];
  const float* pos  = (const float*)d_in[4];
  const float* q_w  = (const float*)d_in[5];
  const float* q_b  = (const float*)d_in[6];
  const float* kv_w = (const float*)d_in[7];
  const float* kv_b = (const float*)d_in[8];
  const float* p_w  = (const float*)d_in[9];
  const float* p_b  = (const float*)d_in[10];
  float* out = (float*)d_out;

  char* w = (char*)d_ws;
  unsigned short* Qp   = (unsigned short*)(w);              // 16.8 MB (b,h,Lq,64)
  unsigned short* Kp   = (unsigned short*)(w + 16777216);   // 24.1 MB (b,h,LKVP,64) swz
  unsigned short* Vt   = (unsigned short*)(w + 40894464);   // 18.1 MB (b,h,48,LKVP) swz
  unsigned short* X    = (unsigned short*)(w + 58982400);   // 12.6 MB (B*LQ,384) swz — aliases qb
  unsigned short* qb   = X;                                 //   (dead before attn writes X)
  unsigned short* posb = (unsigned short*)(w + 71565312);   // 24.1 MB bf16 pos (fallback)
  unsigned short* kvb  = (unsigned short*)(w + 95682560);   // 17.5 MB
  unsigned short* qwb  = (unsigned short*)(w + 113180672);  // 0.3 MB
  unsigned short* kvwb = (unsigned short*)(w + 113475584);  // 0.6 MB
  unsigned short* pwb  = (unsigned short*)(w + 114065408);  // 0.3 MB -> end 114360320
  float* posf          = (float*)(w + POSF_OFF);            // 48.2 MB f32 pos (if ws fits)

  const int f32pos = (ws_size >= POSF_END) ? 1 : 0;  // launch-constant: capture-safe

  prep_all<<<9536, 256, 0, stream>>>(q, kv, q_w, kv_w, p_w, pos, qb, kvb, qwb, kvwb,
                                     pwb, Qp, Kp, Vt, posb, posf, f32pos);
  proj_qkv<<<1452, 256, 0, stream>>>(qb, qwb, q_b, kvb, kvwb, kv_b, tem, srch,
                                     Qp, Kp, Vt);
  if (f32pos)
    attn_fwd<1><<<1024, 256, 0, stream>>>(posb, posf, Qp, Kp, Vt, X);
  else
    attn_fwd<0><<<1024, 256, 0, stream>>>(posb, posf, Qp, Kp, Vt, X);
  proj_out<<<384, 256, 0, stream>>>(X, pwb, p_b, out);
}

// Round 17
// 204.967 us; speedup vs baseline: 1.1794x; 1.1794x over previous
//
#include <hip/hip_runtime.h>
#include <stdint.h>

#define NB 16
#define NH 8
#define LQ 1024
#define LKV 1424
#define LKVP 1472
#define DIMC 384
#define NKVT 23
#define TEM 400
#define QSCALE 0.20823509f       // (1/sqrt(48)) * log2(e)
#define LOG2E_F 1.4426950408889634f
#define POSF_OFF 114360320ull
#define POSF_END 162594816ull

typedef __attribute__((ext_vector_type(4))) float f32x4;
typedef __attribute__((ext_vector_type(8))) short bf16x8;
typedef __attribute__((ext_vector_type(4))) unsigned short us4;
typedef __attribute__((ext_vector_type(2))) unsigned int u32x2;
typedef __attribute__((ext_vector_type(4))) unsigned int u32x4;

__device__ __forceinline__ unsigned short f2b(float f) {
  unsigned int u = __builtin_bit_cast(unsigned int, f);
  u += 0x7fffu + ((u >> 16) & 1u);  // round-to-nearest-even
  return (unsigned short)(u >> 16);
}

__device__ __forceinline__ void gload_lds16(const void* gsrc, void* ldst) {
  __builtin_amdgcn_global_load_lds(
      (const __attribute__((address_space(1))) void*)gsrc,
      (__attribute__((address_space(3))) void*)ldst, 16, 0, 0);
}

// ---------- merged prep: pos-pack (FIRST, t-parallel) + convert(5) + pad-zero ----------
// pos section: blocks [0,3072) = (q16,h,tchunk); ONE t per wave (6x wider than R16,
// scheduled first so the latency-bound transpose overlaps the streaming conv blocks).
__global__ __launch_bounds__(256) void prep_all(
    const float* __restrict__ q, const float* __restrict__ kv,
    const float* __restrict__ qw, const float* __restrict__ kvw,
    const float* __restrict__ pw, const float* __restrict__ pos,
    unsigned short* __restrict__ qb, unsigned short* __restrict__ kvb,
    unsigned short* __restrict__ qwb, unsigned short* __restrict__ kvwb,
    unsigned short* __restrict__ pwb, unsigned short* __restrict__ Qp,
    unsigned short* __restrict__ Kp, unsigned short* __restrict__ Vt,
    unsigned short* __restrict__ posb, float* __restrict__ posf, int f32pos) {
  __shared__ float lds[4][1024];
  const int bid = blockIdx.x;
  if (bid < 3072) {  // ---- pos pack: coalesced reads, LDS transpose, fragment order ----
    const int q16 = bid & 63, h = (bid >> 6) & 7, chunk = bid >> 9;
    const int wave = threadIdx.x >> 6, lane = threadIdx.x & 63;
    const int l16 = lane & 15, g = lane >> 4;
    const int t = chunk * 4 + wave;
    if (t < NKVT) {
      float* L = &lds[wave][0];
#pragma unroll
      for (int i = 0; i < 4; ++i) {
        const int row = i * 4 + g;
        const int gcol = t * 64 + l16 * 4;
        f32x4 v;
        if (gcol < LKV) {
          v = *(const f32x4*)(pos + ((size_t)h * LQ + q16 * 16 + row) * LKV + gcol);
          v *= LOG2E_F;
        } else {
          f32x4 neg = {-1e30f, -1e30f, -1e30f, -1e30f};
          v = neg;
        }
        *(f32x4*)(L + row * 64 + ((l16 ^ (row & 7)) << 2)) = v;
      }
      if (f32pos) {
        float* op = posf + ((((size_t)h * 64 + q16) * NKVT + t) * 64 + lane) * 16;
#pragma unroll
        for (int ni = 0; ni < 4; ++ni) {
          f32x4 wv = *(const f32x4*)(L + l16 * 64 + (((4 * ni + g) ^ (l16 & 7)) << 2));
          *(f32x4*)(op + 4 * ni) = wv;
        }
      } else {
        unsigned short vals[16];
#pragma unroll
        for (int ni = 0; ni < 4; ++ni) {
          f32x4 wv = *(const f32x4*)(L + l16 * 64 + (((4 * ni + g) ^ (l16 & 7)) << 2));
#pragma unroll
          for (int rr = 0; rr < 4; ++rr) vals[4 * ni + rr] = f2b(wv[rr]);
        }
        unsigned short* op = posb + ((((size_t)h * 64 + q16) * NKVT + t) * 64 + lane) * 16;
        bf16x8 a, b;
#pragma unroll
        for (int k = 0; k < 8; ++k) { a[k] = (short)vals[k]; b[k] = (short)vals[8 + k]; }
        *(bf16x8*)op = a;
        *(bf16x8*)(op + 8) = b;
      }
    }
  } else if (bid < 3072 + 7632) {  // ---- conv: f32 [R][384] -> bf16 pre-swizzled ----
    int i = (bid - 3072) * 256 + threadIdx.x;
    const float* src;
    unsigned short* dst;
    if (i < 16384 * 48) { src = q; dst = qb; }
    else if (i < 39168 * 48) { i -= 16384 * 48; src = kv; dst = kvb; }
    else if (i < 39552 * 48) { i -= 39168 * 48; src = qw; dst = qwb; }
    else if (i < 40320 * 48) { i -= 39552 * 48; src = kvw; dst = kvwb; }
    else { i -= 40320 * 48; src = pw; dst = pwb; }
    int row = i / 48, ch = i - row * 48;
    const float* sp = src + (size_t)row * DIMC + ch * 8;
    f32x4 x = *(const f32x4*)sp;
    f32x4 y = *(const f32x4*)(sp + 4);
    bf16x8 o;
    o[0] = (short)f2b(x[0]); o[1] = (short)f2b(x[1]);
    o[2] = (short)f2b(x[2]); o[3] = (short)f2b(x[3]);
    o[4] = (short)f2b(y[0]); o[5] = (short)f2b(y[1]);
    o[6] = (short)f2b(y[2]); o[7] = (short)f2b(y[3]);
    int blk = ch >> 3, c3 = (ch & 7) ^ (row & 7);
    *(bf16x8*)(dst + (size_t)row * DIMC + blk * 64 + c3 * 8) = o;
  } else {  // ---- exact pad zeroing ----
    int i = (bid - 10704) * 256 + threadIdx.x;
    u32x4 z = {0u, 0u, 0u, 0u};
    if (i < 131072) {
      *(u32x4*)(Qp + (size_t)i * 64 + 48) = z;
      *(u32x4*)(Qp + (size_t)i * 64 + 56) = z;
    } else if (i < 131072 + 188416) {
      int r = i - 131072;
      int s = r % LKVP;
      unsigned short* row = Kp + (size_t)r * 64;
      if (s < LKV) {
        *(u32x4*)(row + (6 ^ (s & 7)) * 8) = z;
        *(u32x4*)(row + (7 ^ (s & 7)) * 8) = z;
      } else {
#pragma unroll
        for (int c = 0; c < 64; c += 8) *(u32x4*)(row + c) = z;
      }
    } else if (i < 131072 + 188416 + 36864) {
      int j = i - 319488;
      int row = j / 6, x = 2 + j - (j / 6) * 6;
      int d = row % 48;
      *(u32x4*)(Vt + (size_t)row * LKVP + 1408 + ((x ^ d) & 7) * 8) = z;
    }
  }
}

// ---------- projection GEMM body: 128x128 tile, BK=64, gload_lds staging ----------
template <int MODE>
__device__ __forceinline__ void proj_body(
    unsigned short* Ash, unsigned short* Bsh, int n0, int m0,
    const unsigned short* __restrict__ A, const unsigned short* __restrict__ Wb,
    const float* __restrict__ bias, const float* __restrict__ tem,
    const float* __restrict__ srch, unsigned short* __restrict__ Oq,
    unsigned short* __restrict__ Ok, unsigned short* __restrict__ Ovt,
    float* __restrict__ Of) {
  const int tid = threadIdx.x;
  const int lane = tid & 63, l16 = lane & 15, g = lane >> 4;
  const int wave = tid >> 6, wm = wave >> 1, wn = wave & 1;

  f32x4 acc[4][4];
#pragma unroll
  for (int i = 0; i < 4; ++i)
#pragma unroll
    for (int j = 0; j < 4; ++j) { f32x4 z = {0.f, 0.f, 0.f, 0.f}; acc[i][j] = z; }

  const char* Abase = (const char*)A + (size_t)m0 * 768;
  const char* Bbase = (const char*)Wb + (size_t)n0 * 768;

  for (int ks = 0; ks < 6; ++ks) {
    __syncthreads();
#pragma unroll
    for (int rnd = 0; rnd < 4; ++rnd) {
      int idx = tid + rnd * 256;
      int row = idx >> 3, chunk = idx & 7;
      gload_lds16(Abase + (size_t)row * 768 + ks * 128 + chunk * 16,
                  (char*)Ash + idx * 16);
    }
#pragma unroll
    for (int rnd = 0; rnd < 4; ++rnd) {
      int idx = tid + rnd * 256;
      int row = idx >> 3, chunk = idx & 7;
      gload_lds16(Bbase + (size_t)row * 768 + ks * 128 + chunk * 16,
                  (char*)Bsh + idx * 16);
    }
    asm volatile("s_waitcnt vmcnt(0)" ::: "memory");
    __syncthreads();
#pragma unroll
    for (int kk = 0; kk < 2; ++kk) {
      bf16x8 a[4], bb[4];
#pragma unroll
      for (int mi = 0; mi < 4; ++mi) {
        int row = wm * 64 + mi * 16 + l16;
        a[mi] = *(const bf16x8*)((char*)Ash + row * 128 + (((g + 4 * kk) ^ (row & 7)) << 4));
      }
#pragma unroll
      for (int ni = 0; ni < 4; ++ni) {
        int row = wn * 64 + ni * 16 + l16;
        bb[ni] = *(const bf16x8*)((char*)Bsh + row * 128 + (((g + 4 * kk) ^ (row & 7)) << 4));
      }
#pragma unroll
      for (int mi = 0; mi < 4; ++mi)
#pragma unroll
        for (int ni = 0; ni < 4; ++ni)
          acc[mi][ni] = __builtin_amdgcn_mfma_f32_16x16x32_bf16(a[mi], bb[ni], acc[mi][ni], 0, 0, 0);
    }
  }

#pragma unroll
  for (int mi = 0; mi < 4; ++mi) {
    const int m_g0 = m0 + wm * 64 + mi * 16 + 4 * g;
#pragma unroll
    for (int ni = 0; ni < 4; ++ni) {
      const int n_g = n0 + wn * 64 + ni * 16 + l16;
      const float bv = bias[n_g];
      if (MODE == 0) {
        const int hh = n_g / 48, d = n_g - hh * 48;
#pragma unroll
        for (int r = 0; r < 4; ++r) {
          const int m_g = m_g0 + r;
          const int b = m_g >> 10, m = m_g & 1023;
          Oq[(((size_t)b * NH + hh) * LQ + m) * 64 + d] = f2b((acc[mi][ni][r] + bv) * QSCALE);
        }
      } else if (MODE == 2) {
#pragma unroll
        for (int r = 0; r < 4; ++r)
          Of[(size_t)(m_g0 + r) * DIMC + n_g] = acc[mi][ni][r] + bv;
      } else {
        const int b = m_g0 / LKV, s0 = m_g0 - b * LKV;
        if (n_g < DIMC) {
          const int hh = n_g / 48, d = n_g - hh * 48;
#pragma unroll
          for (int r = 0; r < 4; ++r) {
            const int s = s0 + r;
            const int dsw = (d & 7) | ((((d >> 3) ^ (s & 7)) & 7) << 3);
            Ok[(((size_t)b * NH + hh) * LKVP + s) * 64 + dsw] = f2b(acc[mi][ni][r] + bv);
          }
        } else {
          const int c = n_g - DIMC, hh = c / 48, d = c - hh * 48;
          const float* mb = (s0 < TEM)
                                ? tem + ((size_t)b * TEM + s0) * DIMC + c
                                : srch + ((size_t)b * (LKV - TEM) + (s0 - TEM)) * DIMC + c;
          const int off = s0 & 63;
          const int soff = (s0 & ~63) | ((((off >> 3) ^ d) & 7) << 3) | (off & 7);
          us4 pk;
#pragma unroll
          for (int r = 0; r < 4; ++r)
            pk[r] = f2b(acc[mi][ni][r] + bv + mb[(size_t)r * DIMC]);
          *(us4*)(Ovt + (((size_t)b * NH + hh) * 48 + d) * LKVP + soff) = pk;
        }
      }
    }
  }
}

// fused Q-proj (384 blocks) + KV-proj (1068 blocks)
__global__ __launch_bounds__(256) void proj_qkv(
    const unsigned short* __restrict__ qb, const unsigned short* __restrict__ qwb,
    const float* __restrict__ q_b, const unsigned short* __restrict__ kvb,
    const unsigned short* __restrict__ kvwb, const float* __restrict__ kv_b,
    const float* __restrict__ tem, const float* __restrict__ srch,
    unsigned short* __restrict__ Qp, unsigned short* __restrict__ Ok,
    unsigned short* __restrict__ Ovt) {
  __shared__ unsigned short Ash[128 * 64];
  __shared__ unsigned short Bsh[128 * 64];
  const int bid = blockIdx.x;
  if (bid < 384) {
    proj_body<0>(Ash, Bsh, (bid % 3) * 128, (bid / 3) * 128, qb, qwb, q_b,
                 nullptr, nullptr, Qp, nullptr, nullptr, nullptr);
  } else {
    const int r = bid - 384;
    proj_body<1>(Ash, Bsh, (r % 6) * 128, (r / 6) * 128, kvb, kvwb, kv_b,
                 tem, srch, nullptr, Ok, Ovt, nullptr);
  }
}

__global__ __launch_bounds__(256) void proj_out(
    const unsigned short* __restrict__ X, const unsigned short* __restrict__ pwb,
    const float* __restrict__ p_b, float* __restrict__ out) {
  __shared__ unsigned short Ash[128 * 64];
  __shared__ unsigned short Bsh[128 * 64];
  proj_body<2>(Ash, Bsh, (blockIdx.x % 3) * 128, (blockIdx.x / 3) * 128, X, pwb, p_b,
               nullptr, nullptr, nullptr, nullptr, nullptr, out);
}

// ---------------- flash attention (R16-verified, byte-identical) ----------------
__device__ __forceinline__ void stage_tile(const char* kbase, const char* vbase, int t,
                                           char* kdst, char* vdst, int wave, int lane) {
  const char* ks = kbase + (size_t)t * 8192 + wave * 2048 + lane * 16;
  char* kd = kdst + wave * 2048;
  gload_lds16(ks, kd);
  gload_lds16(ks + 1024, kd + 1024);
  if (wave < 3) {  // V tile: 48 rows x 128B
    const char* vs = vbase + (size_t)(wave * 16 + (lane >> 3)) * (LKVP * 2) +
                     (size_t)t * 128 + (lane & 7) * 16;
    char* vd = vdst + wave * 2048;
    gload_lds16(vs, vd);
    gload_lds16(vs + 8 * (LKVP * 2), vd + 1024);
  }
}

__device__ __forceinline__ void exp16(f32x4 (&sx)[4]) {
#pragma unroll
  for (int ni = 0; ni < 4; ++ni)
#pragma unroll
    for (int r = 0; r < 4; ++r) sx[ni][r] = exp2f(sx[ni][r]);
}

__device__ __forceinline__ void packP(const f32x4 (&sx)[4], char* pbase, int swz, int g,
                                      bf16x8& af0, bf16x8& af1) {
#pragma unroll
  for (int ni = 0; ni < 4; ++ni) {
    float e0 = sx[ni][0], e1 = sx[ni][1], e2 = sx[ni][2], e3 = sx[ni][3];
    unsigned int lo, hi;
    asm("v_cvt_pk_bf16_f32 %0, %1, %2" : "=v"(lo) : "v"(e0), "v"(e1));
    asm("v_cvt_pk_bf16_f32 %0, %1, %2" : "=v"(hi) : "v"(e2), "v"(e3));
    u32x2 pk = {lo, hi};
    *(u32x2*)(pbase + ((32 * ni + 8 * g) ^ swz)) = pk;
  }
  af0 = *(const bf16x8*)(pbase + ((16 * g) ^ swz));
  af1 = *(const bf16x8*)(pbase + ((64 + 16 * g) ^ swz));
}

__device__ __forceinline__ void unpack_pos(const u32x4& w0, const u32x4& w1,
                                           f32x4 (&s)[4]) {
#pragma unroll
  for (int k = 0; k < 4; ++k) {
    const int ni = k >> 1, j2 = (k & 1) * 2;
    unsigned int a = w0[k], b = w1[k];
    s[ni][j2]         = __builtin_bit_cast(float, a << 16);
    s[ni][j2 + 1]     = __builtin_bit_cast(float, a & 0xffff0000u);
    s[ni + 2][j2]     = __builtin_bit_cast(float, b << 16);
    s[ni + 2][j2 + 1] = __builtin_bit_cast(float, b & 0xffff0000u);
  }
}

template <int F32POS>
__global__ __launch_bounds__(256, 4) void attn_fwd(
    const unsigned short* __restrict__ posb, const float* __restrict__ posf,
    const unsigned short* __restrict__ Qp, const unsigned short* __restrict__ Kp,
    const unsigned short* __restrict__ Vt, unsigned short* __restrict__ X) {
  __shared__ unsigned short Ksh[2][64 * 64];
  __shared__ unsigned short Vsh[2][48 * 64];
  __shared__ unsigned short Psh[4][16 * 64];

  const int tid = threadIdx.x;
  const int lane = tid & 63, l16 = lane & 15, g = lane >> 4;
  const int wave = tid >> 6;
  const int bid = blockIdx.x;  // xcd = bid%8 = h (L2 locality)
  const int bh = bid & 127, qt = bid >> 7;
  const int b = bh >> 3, h = bh & 7;
  const int qrow = qt * 128 + wave * 32;

  bf16x8 qf[2][2];
#pragma unroll
  for (int qs = 0; qs < 2; ++qs) {
    const unsigned short* qb = Qp + ((size_t)bh * LQ + qrow + qs * 16 + l16) * 64 + 8 * g;
    qf[qs][0] = *(const bf16x8*)qb;
    qf[qs][1] = *(const bf16x8*)(qb + 32);
  }

  bf16x8 ones;
#pragma unroll
  for (int i = 0; i < 8; ++i) ones[i] = (short)0x3F80;  // bf16 1.0

  f32x4 lsum[2];
  f32x4 o[2][3];
#pragma unroll
  for (int qs = 0; qs < 2; ++qs) {
    f32x4 z = {0.f, 0.f, 0.f, 0.f};
    lsum[qs] = z;
#pragma unroll
    for (int d = 0; d < 3; ++d) o[qs][d] = z;
  }

  const char* kbase = (const char*)(Kp + (size_t)bh * LKVP * 64);
  const char* vbase = (const char*)(Vt + (size_t)bh * 48 * LKVP);
  const int q16b = qt * 8 + wave * 2;
  const unsigned short* pq0 = posb + (((size_t)h * 64 + q16b) * NKVT) * 1024 + lane * 16;
  const unsigned short* pq1 = pq0 + (size_t)NKVT * 1024;
  const float* pf0 = posf + (((size_t)h * 64 + q16b) * NKVT) * 1024 + lane * 16;
  const float* pf1 = pf0 + (size_t)NKVT * 1024;
  char* pbase = (char*)&Psh[wave][0] + l16 * 128;
  const int swz = (l16 & 7) << 4;

  stage_tile(kbase, vbase, 0, (char*)&Ksh[0][0], (char*)&Vsh[0][0], wave, lane);

  f32x4 s0[4], s1[4];
  u32x4 w0, w1, w2, w3;
  if constexpr (F32POS) {
#pragma unroll
    for (int ni = 0; ni < 4; ++ni) {
      s0[ni] = *(const f32x4*)(pf0 + 4 * ni);
      s1[ni] = *(const f32x4*)(pf1 + 4 * ni);
    }
    pf0 += 1024; pf1 += 1024;
  } else {
    w0 = *(const u32x4*)(pq0);
    w1 = *(const u32x4*)(pq0 + 8);
    w2 = *(const u32x4*)(pq1);
    w3 = *(const u32x4*)(pq1 + 8);
    pq0 += 1024; pq1 += 1024;
  }

  asm volatile("s_waitcnt vmcnt(0)" ::: "memory");
  __syncthreads();

  int buf = 0;
  for (int t = 0; t < NKVT; ++t) {
    if (t + 1 < NKVT)
      stage_tile(kbase, vbase, t + 1, (char*)&Ksh[buf ^ 1][0], (char*)&Vsh[buf ^ 1][0],
                 wave, lane);

    if constexpr (!F32POS) {
      unpack_pos(w0, w1, s0);
      unpack_pos(w2, w3, s1);
      if (t + 1 < NKVT) {
        w0 = *(const u32x4*)(pq0);
        w1 = *(const u32x4*)(pq0 + 8);
        w2 = *(const u32x4*)(pq1);
        w3 = *(const u32x4*)(pq1 + 8);
        pq0 += 1024; pq1 += 1024;
      }
    }

    // QK^T swapped (q = l16 lane-local), C initialized with pos
#pragma unroll
    for (int ni = 0; ni < 4; ++ni) {
      const int krow = ni * 16 + l16;
      const char* kr = (const char*)&Ksh[buf][0] + krow * 128;
      bf16x8 kf0 = *(const bf16x8*)(kr + ((g ^ (krow & 7)) << 4));
      bf16x8 kf1 = *(const bf16x8*)(kr + (((g + 4) ^ (krow & 7)) << 4));
      s0[ni] = __builtin_amdgcn_mfma_f32_16x16x32_bf16(kf0, qf[0][0], s0[ni], 0, 0, 0);
      s0[ni] = __builtin_amdgcn_mfma_f32_16x16x32_bf16(kf1, qf[0][1], s0[ni], 0, 0, 0);
      s1[ni] = __builtin_amdgcn_mfma_f32_16x16x32_bf16(kf0, qf[1][0], s1[ni], 0, 0, 0);
      s1[ni] = __builtin_amdgcn_mfma_f32_16x16x32_bf16(kf1, qf[1][1], s1[ni], 0, 0, 0);
    }

    // P = exp2(s) (bounded logits); l via ones-MFMA on matrix pipe.
    exp16(s0);
    bf16x8 af00, af01, af10, af11;
    packP(s0, pbase, swz, g, af00, af01);
    if constexpr (F32POS) {
      if (t + 1 < NKVT) {  // s0 dead after pack — reload pos(t+1) directly
#pragma unroll
        for (int ni = 0; ni < 4; ++ni) s0[ni] = *(const f32x4*)(pf0 + 4 * ni);
        pf0 += 1024;
      }
    }
    exp16(s1);
#pragma unroll
    for (int dn = 0; dn < 3; ++dn) {
      const int vr = 16 * dn + l16;
      const char* vrp = (const char*)&Vsh[buf][0] + vr * 128;
      bf16x8 vf0 = *(const bf16x8*)(vrp + ((g ^ (vr & 7)) << 4));
      bf16x8 vf1 = *(const bf16x8*)(vrp + (((g + 4) ^ (vr & 7)) << 4));
      o[0][dn] = __builtin_amdgcn_mfma_f32_16x16x32_bf16(af00, vf0, o[0][dn], 0, 0, 0);
      o[0][dn] = __builtin_amdgcn_mfma_f32_16x16x32_bf16(af01, vf1, o[0][dn], 0, 0, 0);
    }
    lsum[0] = __builtin_amdgcn_mfma_f32_16x16x32_bf16(af00, ones, lsum[0], 0, 0, 0);
    lsum[0] = __builtin_amdgcn_mfma_f32_16x16x32_bf16(af01, ones, lsum[0], 0, 0, 0);
    packP(s1, pbase, swz, g, af10, af11);
    if constexpr (F32POS) {
      if (t + 1 < NKVT) {
#pragma unroll
        for (int ni = 0; ni < 4; ++ni) s1[ni] = *(const f32x4*)(pf1 + 4 * ni);
        pf1 += 1024;
      }
    }
#pragma unroll
    for (int dn = 0; dn < 3; ++dn) {
      const int vr = 16 * dn + l16;
      const char* vrp = (const char*)&Vsh[buf][0] + vr * 128;
      bf16x8 vf0 = *(const bf16x8*)(vrp + ((g ^ (vr & 7)) << 4));
      bf16x8 vf1 = *(const bf16x8*)(vrp + (((g + 4) ^ (vr & 7)) << 4));
      o[1][dn] = __builtin_amdgcn_mfma_f32_16x16x32_bf16(af10, vf0, o[1][dn], 0, 0, 0);
      o[1][dn] = __builtin_amdgcn_mfma_f32_16x16x32_bf16(af11, vf1, o[1][dn], 0, 0, 0);
    }
    lsum[1] = __builtin_amdgcn_mfma_f32_16x16x32_bf16(af10, ones, lsum[1], 0, 0, 0);
    lsum[1] = __builtin_amdgcn_mfma_f32_16x16x32_bf16(af11, ones, lsum[1], 0, 0, 0);

    asm volatile("s_waitcnt vmcnt(0)" ::: "memory");
    __syncthreads();
    buf ^= 1;
  }

  // epilogue: lsum[qs][r] indexed by q = 4g+r (same C-layout as o) — no shfl
#pragma unroll
  for (int qs = 0; qs < 2; ++qs) {
#pragma unroll
    for (int r = 0; r < 4; ++r) {
      const float ib = 1.f / lsum[qs][r];
      const int m = qrow + qs * 16 + 4 * g + r;
#pragma unroll
      for (int dn = 0; dn < 3; ++dn) {
        const int c = h * 48 + 16 * dn + l16;
        const int cs = (c & ~63) | (c & 7) | ((((c >> 3) & 7) ^ (m & 7)) << 3);
        X[((size_t)b * LQ + m) * DIMC + cs] = f2b(o[qs][dn][r] * ib);
      }
    }
  }
}

// ---------------- launch ----------------
extern "C" void kernel_launch(void* const* d_in, const int* in_sizes, int n_in,
                              void* d_out, int out_size, void* d_ws, size_t ws_size,
                              hipStream_t stream) {
  const float* tem  = (const float*)d_in[0];
  const float* srch = (const float*)d_in[1];
  const float* q    = (const float*)d_in[2];
  const float* kv   = (const float*)d_in[3];
  const float* pos  = (const float*)d_in[4];
  const float* q_w  = (const float*)d_in[5];
  const float* q_b  = (const float*)d_in[6];
  const float* kv_w = (const float*)d_in[7];
  const float* kv_b = (const float*)d_in[8];
  const float* p_w  = (const float*)d_in[9];
  const float* p_b  = (const float*)d_in[10];
  float* out = (float*)d_out;

  char* w = (char*)d_ws;
  unsigned short* Qp   = (unsigned short*)(w);              // 16.8 MB (b,h,Lq,64)
  unsigned short* Kp   = (unsigned short*)(w + 16777216);   // 24.1 MB (b,h,LKVP,64) swz
  unsigned short* Vt   = (unsigned short*)(w + 40894464);   // 18.1 MB (b,h,48,LKVP) swz
  unsigned short* X    = (unsigned short*)(w + 58982400);   // 12.6 MB (B*LQ,384) swz — aliases qb
  unsigned short* qb   = X;                                 //   (dead before attn writes X)
  unsigned short* posb = (unsigned short*)(w + 71565312);   // 24.1 MB bf16 pos (fallback)
  unsigned short* kvb  = (unsigned short*)(w + 95682560);   // 17.5 MB
  unsigned short* qwb  = (unsigned short*)(w + 113180672);  // 0.3 MB
  unsigned short* kvwb = (unsigned short*)(w + 113475584);  // 0.6 MB
  unsigned short* pwb  = (unsigned short*)(w + 114065408);  // 0.3 MB -> end 114360320
  float* posf          = (float*)(w + POSF_OFF);            // 48.2 MB f32 pos (if ws fits)

  const int f32pos = (ws_size >= POSF_END) ? 1 : 0;  // launch-constant: capture-safe

  prep_all<<<12096, 256, 0, stream>>>(q, kv, q_w, kv_w, p_w, pos, qb, kvb, qwb, kvwb,
                                      pwb, Qp, Kp, Vt, posb, posf, f32pos);
  proj_qkv<<<1452, 256, 0, stream>>>(qb, qwb, q_b, kvb, kvwb, kv_b, tem, srch,
                                     Qp, Kp, Vt);
  if (f32pos)
    attn_fwd<1><<<1024, 256, 0, stream>>>(posb, posf, Qp, Kp, Vt, X);
  else
    attn_fwd<0><<<1024, 256, 0, stream>>>(posb, posf, Qp, Kp, Vt, X);
  proj_out<<<384, 256, 0, stream>>>(X, pwb, p_b, out);
}